// Round 1
// baseline (432.656 us; speedup 1.0000x reference)
//
#include <hip/hip_runtime.h>
#include <math.h>

#define W 512
#define H 512
#define NPIX (W*H)
#define RAD 10
#define KS 21
#define CRF_EPS 1e-4f

struct W21 { float w[KS]; };

__device__ __forceinline__ float4 f4(float x, float y, float z, float w_) {
    return make_float4(x, y, z, w_);
}
__device__ __forceinline__ float4 fma4(float s, float4 a, float4 acc) {
    acc.x = fmaf(s, a.x, acc.x); acc.y = fmaf(s, a.y, acc.y);
    acc.z = fmaf(s, a.z, acc.z); acc.w = fmaf(s, a.w, acc.w);
    return acc;
}

// ---- setup kernels ----

// 1-D in-bounds weight sums: S(x) = sum_{d: 0<=x+d<W} w[d]
__global__ __launch_bounds__(512) void k_tables(W21 wg, W21 wu, float* Sg, float* Su) {
    int x = threadIdx.x;
    float sg = 0.f, su = 0.f;
    #pragma unroll
    for (int d = -RAD; d <= RAD; ++d) {
        int xx = x + d;
        if (xx >= 0 && xx < W) { sg += wg.w[d + RAD]; su += wu.w[d + RAD]; }
    }
    Sg[x] = sg; Su[x] = su;
}

// gray = image . rgb_w ; Q0 = softmax(-unary)
__global__ __launch_bounds__(256) void k_init(const float* img, const float4* unary,
                                              float* gray, float4* Q) {
    int p = blockIdx.x * 256 + threadIdx.x;
    if (p >= NPIX) return;
    float r = img[3 * p], g = img[3 * p + 1], b = img[3 * p + 2];
    gray[p] = 0.2989f * r + 0.5870f * g + 0.1140f * b;
    float4 u = unary[p];
    float mn = fminf(fminf(u.x, u.y), fminf(u.z, u.w));
    float ex = expf(mn - u.x), ey = expf(mn - u.y), ez = expf(mn - u.z), ew = expf(mn - u.w);
    float inv = 1.f / (ex + ey + ez + ew);
    Q[p] = f4(ex * inv, ey * inv, ez * inv, ew * inv);
}

// horizontal guided conv of gray and gray^2 -> float2 {hI, hII}
__global__ __launch_bounds__(256) void k_hconv_gray(const float* gray, float2* hII, W21 wu) {
    __shared__ float sg[256 + 2 * RAD];
    int x0 = blockIdx.x * 256, y = blockIdx.y, t = threadIdx.x;
    const float* row = gray + y * W;
    for (int i = t; i < 256 + 2 * RAD; i += 256) {
        int x = x0 - RAD + i;
        sg[i] = (x >= 0 && x < W) ? row[x] : 0.f;
    }
    __syncthreads();
    float aI = 0.f, aII = 0.f;
    #pragma unroll
    for (int d = 0; d < KS; ++d) {
        float v = sg[t + d];
        aI  = fmaf(wu.w[d], v, aI);
        aII = fmaf(wu.w[d] * v, v, aII);
    }
    hII[y * W + x0 + t] = make_float2(aI, aII);
}

// vertical + guided-filter invariants: mean_I, 1/(var+eps), a1,b1 (for bilateral_norm)
__global__ __launch_bounds__(256) void k_v_stats(const float2* hII, const float* gray,
                                                 const float* Su, float* mean_I,
                                                 float* inv_var, float2* a1b1,
                                                 W21 wu, float c0u) {
    int p = blockIdx.x * 256 + threadIdx.x;
    if (p >= NPIX) return;
    int y = p >> 9, x = p & (W - 1);
    float vI = 0.f, vII = 0.f;
    #pragma unroll
    for (int d = -RAD; d <= RAD; ++d) {
        int yy = y + d;
        if (yy >= 0 && yy < H) {
            float2 h = hII[yy * W + x];
            float w = wu.w[d + RAD];
            vI = fmaf(w, h.x, vI); vII = fmaf(w, h.y, vII);
        }
    }
    float gv = gray[p];
    float mI = vI - c0u * gv;
    float mII = vII - c0u * gv * gv;
    float iv = 1.f / ((mII - mI * mI) + CRF_EPS);
    float N = Su[x] * Su[y] - c0u;            // gf(ones), closed form
    float a1 = mI * (1.f - N) * iv;
    float b1 = N - a1 * mI;
    mean_I[p] = mI; inv_var[p] = iv; a1b1[p] = make_float2(a1, b1);
}

// horizontal guided conv of a float2 field
__global__ __launch_bounds__(256) void k_hconv_f2(const float2* src, float2* dst, W21 wu) {
    __shared__ float2 s[256 + 2 * RAD];
    int x0 = blockIdx.x * 256, y = blockIdx.y, t = threadIdx.x;
    const float2* row = src + y * W;
    for (int i = t; i < 256 + 2 * RAD; i += 256) {
        int x = x0 - RAD + i;
        s[i] = (x >= 0 && x < W) ? row[x] : make_float2(0.f, 0.f);
    }
    __syncthreads();
    float ax = 0.f, ay = 0.f;
    #pragma unroll
    for (int d = 0; d < KS; ++d) {
        float2 v = s[t + d];
        ax = fmaf(wu.w[d], v.x, ax); ay = fmaf(wu.w[d], v.y, ay);
    }
    dst[y * W + x0 + t] = make_float2(ax, ay);
}

// vertical of {ha1,hb1} -> inv_bilateral_norm
__global__ __launch_bounds__(256) void k_v_bn(const float2* hab, const float2* a1b1,
                                              const float* gray, float* inv_bn,
                                              W21 wu, float c0u) {
    int p = blockIdx.x * 256 + threadIdx.x;
    if (p >= NPIX) return;
    int y = p >> 9, x = p & (W - 1);
    float va = 0.f, vb = 0.f;
    #pragma unroll
    for (int d = -RAD; d <= RAD; ++d) {
        int yy = y + d;
        if (yy >= 0 && yy < H) {
            float2 h = hab[yy * W + x];
            float w = wu.w[d + RAD];
            va = fmaf(w, h.x, va); vb = fmaf(w, h.y, vb);
        }
    }
    float2 ab = a1b1[p];
    va -= c0u * ab.x; vb -= c0u * ab.y;
    float bn = va * gray[p] + vb;
    inv_bn[p] = 1.f / bn;
}

// ---- iteration kernels ----

// horizontal: gauss(Q), guided(Q), guided(gray*Q)
__global__ __launch_bounds__(256) void k_hconv_Q(const float4* Q, const float* gray,
                                                 float4* hQg, float4* hQu, float4* hIQ,
                                                 W21 wg, W21 wu) {
    __shared__ float4 sq[256 + 2 * RAD];
    __shared__ float4 sgq[256 + 2 * RAD];
    int x0 = blockIdx.x * 256, y = blockIdx.y, t = threadIdx.x;
    int rb = y * W;
    for (int i = t; i < 256 + 2 * RAD; i += 256) {
        int x = x0 - RAD + i;
        float4 q = f4(0.f, 0.f, 0.f, 0.f), gq = q;
        if (x >= 0 && x < W) {
            q = Q[rb + x];
            float g = gray[rb + x];
            gq = f4(g * q.x, g * q.y, g * q.z, g * q.w);
        }
        sq[i] = q; sgq[i] = gq;
    }
    __syncthreads();
    float4 ag = f4(0,0,0,0), aq = f4(0,0,0,0), aiq = f4(0,0,0,0);
    #pragma unroll
    for (int d = 0; d < KS; ++d) {
        float4 q = sq[t + d], gq = sgq[t + d];
        ag  = fma4(wg.w[d], q, ag);
        aq  = fma4(wu.w[d], q, aq);
        aiq = fma4(wu.w[d], gq, aiq);
    }
    int o = rb + x0 + t;
    hQg[o] = ag; hQu[o] = aq; hIQ[o] = aiq;
}

// vertical of the 3 conv sets + elementwise -> a, b, partial(-unary + 3*spatial_out)
__global__ __launch_bounds__(256) void k_v_stage1(const float4* hQg, const float4* hQu,
        const float4* hIQ, const float4* Q, const float* gray, const float* mean_I,
        const float* inv_var, const float* Sg, const float4* unary,
        float4* a_out, float4* b_out, float4* partial,
        W21 wg, W21 wu, float c0g, float c0u) {
    int p = blockIdx.x * 256 + threadIdx.x;
    if (p >= NPIX) return;
    int y = p >> 9, x = p & (W - 1);
    float4 vg = f4(0,0,0,0), mp = f4(0,0,0,0), mip = f4(0,0,0,0);
    #pragma unroll
    for (int d = -RAD; d <= RAD; ++d) {
        int yy = y + d;
        if (yy >= 0 && yy < H) {
            int q = yy * W + x;
            float a = wg.w[d + RAD], b = wu.w[d + RAD];
            vg  = fma4(a, hQg[q], vg);
            mp  = fma4(b, hQu[q], mp);
            mip = fma4(b, hIQ[q], mip);
        }
    }
    float4 Qv = Q[p];
    float gv = gray[p];
    vg  = fma4(-c0g, Qv, vg);             // gauss(Q) center fix
    mp  = fma4(-c0u, Qv, mp);             // gf(Q)
    mip = fma4(-c0u * gv, Qv, mip);       // gf(gray*Q)
    float mI = mean_I[p], iv = inv_var[p];
    float4 a, b;
    a.x = (mip.x - mI * mp.x) * iv; a.y = (mip.y - mI * mp.y) * iv;
    a.z = (mip.z - mI * mp.z) * iv; a.w = (mip.w - mI * mp.w) * iv;
    b.x = mp.x - a.x * mI; b.y = mp.y - a.y * mI;
    b.z = mp.z - a.z * mI; b.w = mp.w - a.w * mI;
    float inv_sn = 1.f / (Sg[x] * Sg[y] - c0g);    // spatial_norm, closed form
    float s3 = 3.f * inv_sn;
    float4 u = unary[p];
    float4 part = f4(fmaf(s3, vg.x, -u.x), fmaf(s3, vg.y, -u.y),
                     fmaf(s3, vg.z, -u.z), fmaf(s3, vg.w, -u.w));
    a_out[p] = a; b_out[p] = b; partial[p] = part;
}

// horizontal guided conv of a and b
__global__ __launch_bounds__(256) void k_hconv_ab(const float4* A, const float4* B,
                                                  float4* hA, float4* hB, W21 wu) {
    __shared__ float4 sa[256 + 2 * RAD];
    __shared__ float4 sb[256 + 2 * RAD];
    int x0 = blockIdx.x * 256, y = blockIdx.y, t = threadIdx.x;
    int rb = y * W;
    for (int i = t; i < 256 + 2 * RAD; i += 256) {
        int x = x0 - RAD + i;
        float4 va = f4(0,0,0,0), vb = va;
        if (x >= 0 && x < W) { va = A[rb + x]; vb = B[rb + x]; }
        sa[i] = va; sb[i] = vb;
    }
    __syncthreads();
    float4 aa = f4(0,0,0,0), ab = f4(0,0,0,0);
    #pragma unroll
    for (int d = 0; d < KS; ++d) {
        aa = fma4(wu.w[d], sa[t + d], aa);
        ab = fma4(wu.w[d], sb[t + d], ab);
    }
    int o = rb + x0 + t;
    hA[o] = aa; hB[o] = ab;
}

// vertical of hA,hB + bilateral message + softmax -> Qout
__global__ __launch_bounds__(256) void k_v_stage2(const float4* hA, const float4* hB,
        const float4* A, const float4* B, const float4* partial, const float* gray,
        const float* inv_bn, float4* Qout, W21 wu, float c0u) {
    int p = blockIdx.x * 256 + threadIdx.x;
    if (p >= NPIX) return;
    int y = p >> 9, x = p & (W - 1);
    float4 va = f4(0,0,0,0), vb = f4(0,0,0,0);
    #pragma unroll
    for (int d = -RAD; d <= RAD; ++d) {
        int yy = y + d;
        if (yy >= 0 && yy < H) {
            int q = yy * W + x;
            float w = wu.w[d + RAD];
            va = fma4(w, hA[q], va);
            vb = fma4(w, hB[q], vb);
        }
    }
    va = fma4(-c0u, A[p], va);
    vb = fma4(-c0u, B[p], vb);
    float gv = gray[p];
    float ibn = 10.f * inv_bn[p];
    float4 part = partial[p];
    float lx = fmaf(fmaf(va.x, gv, vb.x), ibn, part.x);
    float ly = fmaf(fmaf(va.y, gv, vb.y), ibn, part.y);
    float lz = fmaf(fmaf(va.z, gv, vb.z), ibn, part.z);
    float lw = fmaf(fmaf(va.w, gv, vb.w), ibn, part.w);
    float m = fmaxf(fmaxf(lx, ly), fmaxf(lz, lw));
    float ex = expf(lx - m), ey = expf(ly - m), ez = expf(lz - m), ew = expf(lw - m);
    float inv = 1.f / (ex + ey + ez + ew);
    Qout[p] = f4(ex * inv, ey * inv, ez * inv, ew * inv);
}

// ---- host ----

static void make_w_host(double theta, W21* w, float* c0) {
    double tmp[KS], s = 0.0;
    for (int d = -RAD; d <= RAD; ++d) {
        double v = exp(-(double)(d * d) / (2.0 * theta * theta));
        tmp[d + RAD] = v; s += v;
    }
    for (int i = 0; i < KS; ++i) w->w[i] = (float)(tmp[i] / s);
    *c0 = (float)(1.0 / (s * s));   // normalized 2D center weight
}

extern "C" void kernel_launch(void* const* d_in, const int* in_sizes, int n_in,
                              void* d_out, int out_size, void* d_ws, size_t ws_size,
                              hipStream_t stream) {
    const float4* unary = (const float4*)d_in[0];
    const float* image = (const float*)d_in[1];
    float* wsf = (float*)d_ws;

    float*  gray    = wsf;
    float*  mean_I  = wsf + 262144;
    float*  inv_var = wsf + 524288;
    float2* a1b1    = (float2*)(wsf + 786432);
    float*  inv_bn  = wsf + 1310720;
    float*  Sg      = wsf + 1572864;
    float*  Su      = wsf + 1573376;
    float4* Q       = (float4*)(wsf + 1573888);
    float4* partial = (float4*)(wsf + 2622464);
    float4* a_arr   = (float4*)(wsf + 3671040);
    float4* b_arr   = (float4*)(wsf + 4719616);
    float4* h0      = (float4*)(wsf + 5768192);
    float4* h1      = (float4*)(wsf + 6816768);
    float4* h2      = (float4*)(wsf + 7865344);

    W21 wg, wu; float c0g, c0u;
    make_w_host(2.5, &wg, &c0g);
    make_w_host(10.0 / 3.0, &wu, &c0u);

    dim3 bl(256), grEl(NPIX / 256), grH(W / 256, H);

    k_tables<<<dim3(1), dim3(512), 0, stream>>>(wg, wu, Sg, Su);
    k_init<<<grEl, bl, 0, stream>>>(image, unary, gray, Q);
    k_hconv_gray<<<grH, bl, 0, stream>>>(gray, (float2*)h0, wu);
    k_v_stats<<<grEl, bl, 0, stream>>>((const float2*)h0, gray, Su, mean_I, inv_var, a1b1, wu, c0u);
    k_hconv_f2<<<grH, bl, 0, stream>>>((const float2*)a1b1, (float2*)h1, wu);
    k_v_bn<<<grEl, bl, 0, stream>>>((const float2*)h1, a1b1, gray, inv_bn, wu, c0u);

    for (int it = 0; it < 5; ++it) {
        k_hconv_Q<<<grH, bl, 0, stream>>>((const float4*)Q, gray, h0, h1, h2, wg, wu);
        k_v_stage1<<<grEl, bl, 0, stream>>>(h0, h1, h2, (const float4*)Q, gray, mean_I,
                                            inv_var, Sg, unary, a_arr, b_arr, partial,
                                            wg, wu, c0g, c0u);
        k_hconv_ab<<<grH, bl, 0, stream>>>(a_arr, b_arr, h0, h1, wu);
        float4* qdst = (it == 4) ? (float4*)d_out : Q;
        k_v_stage2<<<grEl, bl, 0, stream>>>(h0, h1, a_arr, b_arr, partial, gray,
                                            inv_bn, qdst, wu, c0u);
    }
}

// Round 2
// 275.247 us; speedup vs baseline: 1.5719x; 1.5719x over previous
//
#include <hip/hip_runtime.h>
#include <math.h>

#define W 512
#define H 512
#define NPIX (W*H)
#define RAD 10
#define KS 21
#define CRF_EPS 1e-4f
#define T 4                 // output rows per thread in vertical kernels

struct W21 { float w[KS]; };

__device__ __forceinline__ float4 f4(float x, float y, float z, float w_) {
    return make_float4(x, y, z, w_);
}
__device__ __forceinline__ float4 fma4(float s, float4 a, float4 acc) {
    acc.x = fmaf(s, a.x, acc.x); acc.y = fmaf(s, a.y, acc.y);
    acc.z = fmaf(s, a.z, acc.z); acc.w = fmaf(s, a.w, acc.w);
    return acc;
}
// XCD swizzle: consecutive HW block ids round-robin across 8 XCDs; give each
// XCD a contiguous LOGICAL range so geometric neighbors share an L2.
__device__ __forceinline__ int swz(int b, int N) {
    return (b & 7) * (N >> 3) + (b >> 3);
}

// ---- setup kernels ----

__global__ __launch_bounds__(512) void k_tables(W21 wg, W21 wu, float* Sg, float* Su) {
    int x = threadIdx.x;
    float sg = 0.f, su = 0.f;
    #pragma unroll
    for (int d = -RAD; d <= RAD; ++d) {
        int xx = x + d;
        if (xx >= 0 && xx < W) { sg += wg.w[d + RAD]; su += wu.w[d + RAD]; }
    }
    Sg[x] = sg; Su[x] = su;
}

__global__ __launch_bounds__(256) void k_init(const float* img, const float4* unary,
                                              float* gray, float4* Q) {
    int b = swz(blockIdx.x, NPIX / 256);
    int p = b * 256 + threadIdx.x;
    float r = img[3 * p], g = img[3 * p + 1], bch = img[3 * p + 2];
    gray[p] = 0.2989f * r + 0.5870f * g + 0.1140f * bch;
    float4 u = unary[p];
    float mn = fminf(fminf(u.x, u.y), fminf(u.z, u.w));
    float ex = expf(mn - u.x), ey = expf(mn - u.y), ez = expf(mn - u.z), ew = expf(mn - u.w);
    float inv = 1.f / (ex + ey + ez + ew);
    Q[p] = f4(ex * inv, ey * inv, ez * inv, ew * inv);
}

// horizontal guided conv of gray and gray^2 -> float2 {hI, hII}  (setup-only)
__global__ __launch_bounds__(256) void k_hconv_gray(const float* gray, float2* hII, W21 wu) {
    __shared__ float sg[256 + 2 * RAD];
    int x0 = blockIdx.x * 256, y = blockIdx.y, t = threadIdx.x;
    const float* row = gray + y * W;
    for (int i = t; i < 256 + 2 * RAD; i += 256) {
        int x = x0 - RAD + i;
        sg[i] = (x >= 0 && x < W) ? row[x] : 0.f;
    }
    __syncthreads();
    float aI = 0.f, aII = 0.f;
    #pragma unroll
    for (int d = 0; d < KS; ++d) {
        float v = sg[t + d];
        aI  = fmaf(wu.w[d], v, aI);
        aII = fmaf(wu.w[d] * v, v, aII);
    }
    hII[y * W + x0 + t] = make_float2(aI, aII);
}

__global__ __launch_bounds__(256) void k_v_stats(const float2* hII, const float* gray,
                                                 const float* Su, float* mean_I,
                                                 float* inv_var, float2* a1b1,
                                                 W21 wu, float c0u) {
    int p = blockIdx.x * 256 + threadIdx.x;
    int y = p >> 9, x = p & (W - 1);
    float vI = 0.f, vII = 0.f;
    #pragma unroll
    for (int d = -RAD; d <= RAD; ++d) {
        int yy = y + d;
        if (yy >= 0 && yy < H) {
            float2 h = hII[yy * W + x];
            float w = wu.w[d + RAD];
            vI = fmaf(w, h.x, vI); vII = fmaf(w, h.y, vII);
        }
    }
    float gv = gray[p];
    float mI = vI - c0u * gv;
    float mII = vII - c0u * gv * gv;
    float iv = 1.f / ((mII - mI * mI) + CRF_EPS);
    float N = Su[x] * Su[y] - c0u;
    float a1 = mI * (1.f - N) * iv;
    float b1 = N - a1 * mI;
    mean_I[p] = mI; inv_var[p] = iv; a1b1[p] = make_float2(a1, b1);
}

__global__ __launch_bounds__(256) void k_hconv_f2(const float2* src, float2* dst, W21 wu) {
    __shared__ float2 s[256 + 2 * RAD];
    int x0 = blockIdx.x * 256, y = blockIdx.y, t = threadIdx.x;
    const float2* row = src + y * W;
    for (int i = t; i < 256 + 2 * RAD; i += 256) {
        int x = x0 - RAD + i;
        s[i] = (x >= 0 && x < W) ? row[x] : make_float2(0.f, 0.f);
    }
    __syncthreads();
    float ax = 0.f, ay = 0.f;
    #pragma unroll
    for (int d = 0; d < KS; ++d) {
        float2 v = s[t + d];
        ax = fmaf(wu.w[d], v.x, ax); ay = fmaf(wu.w[d], v.y, ay);
    }
    dst[y * W + x0 + t] = make_float2(ax, ay);
}

__global__ __launch_bounds__(256) void k_v_bn(const float2* hab, const float2* a1b1,
                                              const float* gray, float* inv_bn,
                                              W21 wu, float c0u) {
    int p = blockIdx.x * 256 + threadIdx.x;
    int y = p >> 9, x = p & (W - 1);
    float va = 0.f, vb = 0.f;
    #pragma unroll
    for (int d = -RAD; d <= RAD; ++d) {
        int yy = y + d;
        if (yy >= 0 && yy < H) {
            float2 h = hab[yy * W + x];
            float w = wu.w[d + RAD];
            va = fmaf(w, h.x, va); vb = fmaf(w, h.y, vb);
        }
    }
    float2 ab = a1b1[p];
    va -= c0u * ab.x; vb -= c0u * ab.y;
    inv_bn[p] = 1.f / (va * gray[p] + vb);
}

// ---- iteration kernels ----

// horizontal convs: gauss(Q), guided(Q), guided(gray*Q). One image row per
// block (512 outputs, 256 threads, 2 outputs/thread sharing a 22-tap window).
__global__ __launch_bounds__(256) void k_hconv_Q(const float4* Q, const float* gray,
                                                 float4* hQg, float4* hQu, float4* hIQ,
                                                 W21 wg, W21 wu) {
    __shared__ float4 sq[W + 2 * RAD];
    __shared__ float  sg[W + 2 * RAD];
    int y = swz(blockIdx.x, H);
    int t = threadIdx.x;
    int rb = y * W;
    for (int i = t; i < W + 2 * RAD; i += 256) {
        int x = i - RAD;
        float4 q = f4(0.f, 0.f, 0.f, 0.f); float g = 0.f;
        if (x >= 0 && x < W) { q = Q[rb + x]; g = gray[rb + x]; }
        sq[i] = q; sg[i] = g;
    }
    __syncthreads();
    float4 ag0 = f4(0,0,0,0), aq0 = ag0, aiq0 = ag0;
    float4 ag1 = ag0, aq1 = ag0, aiq1 = ag0;
    int base = 2 * t;
    #pragma unroll
    for (int d = 0; d < KS + 1; ++d) {
        float4 q = sq[base + d]; float g = sg[base + d];
        if (d < KS) {
            ag0  = fma4(wg.w[d], q, ag0);
            aq0  = fma4(wu.w[d], q, aq0);
            aiq0 = fma4(wu.w[d] * g, q, aiq0);
        }
        if (d > 0) {
            ag1  = fma4(wg.w[d - 1], q, ag1);
            aq1  = fma4(wu.w[d - 1], q, aq1);
            aiq1 = fma4(wu.w[d - 1] * g, q, aiq1);
        }
    }
    int o = rb + base;
    hQg[o] = ag0; hQu[o] = aq0; hIQ[o] = aiq0;
    hQg[o + 1] = ag1; hQu[o + 1] = aq1; hIQ[o + 1] = aiq1;
}

// vertical convs (T rows/thread) + pointwise -> a, b, partial
__global__ __launch_bounds__(256) void k_v_stage1(const float4* hQg, const float4* hQu,
        const float4* hIQ, const float4* Q, const float* gray, const float* mean_I,
        const float* inv_var, const float* Sg, const float4* unary,
        float4* a_out, float4* b_out, float4* partial,
        W21 wg, W21 wu, float c0g, float c0u) {
    int L = swz(blockIdx.x, NPIX / (256 * T));   // 256 blocks
    int yband = L >> 1, strip = L & 1;
    int y0 = yband * T;
    int x = strip * 256 + threadIdx.x;
    float4 vg[T], mp[T], mip[T];
    #pragma unroll
    for (int j = 0; j < T; ++j) { vg[j] = f4(0,0,0,0); mp[j] = vg[j]; mip[j] = vg[j]; }
    #pragma unroll
    for (int r = 0; r < T + 2 * RAD; ++r) {
        int yy = y0 - RAD + r;
        if ((unsigned)yy < H) {
            int q = yy * W + x;
            float4 h0 = hQg[q], h1 = hQu[q], h2 = hIQ[q];
            #pragma unroll
            for (int j = 0; j < T; ++j) {
                if (j <= r && r - j <= 2 * RAD) {
                    float a = wg.w[r - j], bw = wu.w[r - j];
                    vg[j]  = fma4(a,  h0, vg[j]);
                    mp[j]  = fma4(bw, h1, mp[j]);
                    mip[j] = fma4(bw, h2, mip[j]);
                }
            }
        }
    }
    float Sgx = Sg[x];
    #pragma unroll
    for (int j = 0; j < T; ++j) {
        int p = (y0 + j) * W + x;
        float4 Qv = Q[p];
        float gv = gray[p];
        float4 g4  = fma4(-c0g, Qv, vg[j]);
        float4 m4  = fma4(-c0u, Qv, mp[j]);
        float4 mi4 = fma4(-c0u * gv, Qv, mip[j]);
        float mI = mean_I[p], iv = inv_var[p];
        float4 a, b;
        a.x = (mi4.x - mI * m4.x) * iv; a.y = (mi4.y - mI * m4.y) * iv;
        a.z = (mi4.z - mI * m4.z) * iv; a.w = (mi4.w - mI * m4.w) * iv;
        b.x = m4.x - a.x * mI; b.y = m4.y - a.y * mI;
        b.z = m4.z - a.z * mI; b.w = m4.w - a.w * mI;
        float s3 = 3.f / (Sgx * Sg[y0 + j] - c0g);
        float4 u = unary[p];
        float4 part = f4(fmaf(s3, g4.x, -u.x), fmaf(s3, g4.y, -u.y),
                         fmaf(s3, g4.z, -u.z), fmaf(s3, g4.w, -u.w));
        a_out[p] = a; b_out[p] = b; partial[p] = part;
    }
}

// horizontal guided conv of a and b; one row/block, 2 outputs/thread
__global__ __launch_bounds__(256) void k_hconv_ab(const float4* A, const float4* B,
                                                  float4* hA, float4* hB, W21 wu) {
    __shared__ float4 sa[W + 2 * RAD];
    __shared__ float4 sb[W + 2 * RAD];
    int y = swz(blockIdx.x, H);
    int t = threadIdx.x;
    int rb = y * W;
    for (int i = t; i < W + 2 * RAD; i += 256) {
        int x = i - RAD;
        float4 va = f4(0,0,0,0), vb = va;
        if (x >= 0 && x < W) { va = A[rb + x]; vb = B[rb + x]; }
        sa[i] = va; sb[i] = vb;
    }
    __syncthreads();
    float4 aa0 = f4(0,0,0,0), ab0 = aa0, aa1 = aa0, ab1 = aa0;
    int base = 2 * t;
    #pragma unroll
    for (int d = 0; d < KS + 1; ++d) {
        float4 va = sa[base + d], vb = sb[base + d];
        if (d < KS) {
            aa0 = fma4(wu.w[d], va, aa0);
            ab0 = fma4(wu.w[d], vb, ab0);
        }
        if (d > 0) {
            aa1 = fma4(wu.w[d - 1], va, aa1);
            ab1 = fma4(wu.w[d - 1], vb, ab1);
        }
    }
    int o = rb + base;
    hA[o] = aa0; hB[o] = ab0;
    hA[o + 1] = aa1; hB[o + 1] = ab1;
}

// vertical convs (T rows/thread) of hA,hB + message + softmax -> Qout
__global__ __launch_bounds__(256) void k_v_stage2(const float4* hA, const float4* hB,
        const float4* A, const float4* B, const float4* partial, const float* gray,
        const float* inv_bn, float4* Qout, W21 wu, float c0u) {
    int L = swz(blockIdx.x, NPIX / (256 * T));
    int yband = L >> 1, strip = L & 1;
    int y0 = yband * T;
    int x = strip * 256 + threadIdx.x;
    float4 va[T], vb[T];
    #pragma unroll
    for (int j = 0; j < T; ++j) { va[j] = f4(0,0,0,0); vb[j] = va[j]; }
    #pragma unroll
    for (int r = 0; r < T + 2 * RAD; ++r) {
        int yy = y0 - RAD + r;
        if ((unsigned)yy < H) {
            int q = yy * W + x;
            float4 ha = hA[q], hb = hB[q];
            #pragma unroll
            for (int j = 0; j < T; ++j) {
                if (j <= r && r - j <= 2 * RAD) {
                    float w = wu.w[r - j];
                    va[j] = fma4(w, ha, va[j]);
                    vb[j] = fma4(w, hb, vb[j]);
                }
            }
        }
    }
    #pragma unroll
    for (int j = 0; j < T; ++j) {
        int p = (y0 + j) * W + x;
        float4 a4 = fma4(-c0u, A[p], va[j]);
        float4 b4 = fma4(-c0u, B[p], vb[j]);
        float gv = gray[p];
        float ibn = 10.f * inv_bn[p];
        float4 part = partial[p];
        float lx = fmaf(fmaf(a4.x, gv, b4.x), ibn, part.x);
        float ly = fmaf(fmaf(a4.y, gv, b4.y), ibn, part.y);
        float lz = fmaf(fmaf(a4.z, gv, b4.z), ibn, part.z);
        float lw = fmaf(fmaf(a4.w, gv, b4.w), ibn, part.w);
        float m = fmaxf(fmaxf(lx, ly), fmaxf(lz, lw));
        float ex = expf(lx - m), ey = expf(ly - m), ez = expf(lz - m), ew = expf(lw - m);
        float inv = 1.f / (ex + ey + ez + ew);
        Qout[p] = f4(ex * inv, ey * inv, ez * inv, ew * inv);
    }
}

// ---- host ----

static void make_w_host(double theta, W21* w, float* c0) {
    double tmp[KS], s = 0.0;
    for (int d = -RAD; d <= RAD; ++d) {
        double v = exp(-(double)(d * d) / (2.0 * theta * theta));
        tmp[d + RAD] = v; s += v;
    }
    for (int i = 0; i < KS; ++i) w->w[i] = (float)(tmp[i] / s);
    *c0 = (float)(1.0 / (s * s));   // normalized 2D center weight
}

extern "C" void kernel_launch(void* const* d_in, const int* in_sizes, int n_in,
                              void* d_out, int out_size, void* d_ws, size_t ws_size,
                              hipStream_t stream) {
    const float4* unary = (const float4*)d_in[0];
    const float* image = (const float*)d_in[1];
    float* wsf = (float*)d_ws;

    float*  gray    = wsf;
    float*  mean_I  = wsf + 262144;
    float*  inv_var = wsf + 524288;
    float2* a1b1    = (float2*)(wsf + 786432);
    float*  inv_bn  = wsf + 1310720;
    float*  Sg      = wsf + 1572864;
    float*  Su      = wsf + 1573376;
    float4* Q       = (float4*)(wsf + 1573888);
    float4* partial = (float4*)(wsf + 2622464);
    float4* a_arr   = (float4*)(wsf + 3671040);
    float4* b_arr   = (float4*)(wsf + 4719616);
    float4* h0      = (float4*)(wsf + 5768192);
    float4* h1      = (float4*)(wsf + 6816768);
    float4* h2      = (float4*)(wsf + 7865344);

    W21 wg, wu; float c0g, c0u;
    make_w_host(2.5, &wg, &c0g);
    make_w_host(10.0 / 3.0, &wu, &c0u);

    dim3 bl(256), grEl(NPIX / 256), grH(W / 256, H);
    dim3 grRow(H);            // one image row per block (pair-output H convs)
    dim3 grV(NPIX / (256 * T));

    k_tables<<<dim3(1), dim3(512), 0, stream>>>(wg, wu, Sg, Su);
    k_init<<<grEl, bl, 0, stream>>>(image, unary, gray, Q);
    k_hconv_gray<<<grH, bl, 0, stream>>>(gray, (float2*)h0, wu);
    k_v_stats<<<grEl, bl, 0, stream>>>((const float2*)h0, gray, Su, mean_I, inv_var, a1b1, wu, c0u);
    k_hconv_f2<<<grH, bl, 0, stream>>>((const float2*)a1b1, (float2*)h1, wu);
    k_v_bn<<<grEl, bl, 0, stream>>>((const float2*)h1, a1b1, gray, inv_bn, wu, c0u);

    for (int it = 0; it < 5; ++it) {
        k_hconv_Q<<<grRow, bl, 0, stream>>>((const float4*)Q, gray, h0, h1, h2, wg, wu);
        k_v_stage1<<<grV, bl, 0, stream>>>(h0, h1, h2, (const float4*)Q, gray, mean_I,
                                           inv_var, Sg, unary, a_arr, b_arr, partial,
                                           wg, wu, c0g, c0u);
        k_hconv_ab<<<grRow, bl, 0, stream>>>(a_arr, b_arr, h0, h1, wu);
        float4* qdst = (it == 4) ? (float4*)d_out : Q;
        k_v_stage2<<<grV, bl, 0, stream>>>(h0, h1, a_arr, b_arr, partial, gray,
                                           inv_bn, qdst, wu, c0u);
    }
}

// Round 3
// 197.722 us; speedup vs baseline: 2.1882x; 1.3921x over previous
//
#include <hip/hip_runtime.h>
#include <math.h>

#define W 512
#define H 512
#define NPIX (W*H)
#define RAD 10
#define KS 21
#define CRF_EPS 1e-4f

// fused-tile geometry: TX x TY outputs per block, halo RAD each side
#define TX 32
#define TY 16
#define CIN (TX + 2*RAD)   // 52 input cols
#define RIN (TY + 2*RAD)   // 36 input rows
#define GX (W / TX)        // 16
#define GY (H / TY)        // 32
#define NBLK (GX*GY)       // 512 blocks = 2/CU

struct W21 { float w[KS]; };

__device__ __forceinline__ float4 f4(float x, float y, float z, float w_) {
    return make_float4(x, y, z, w_);
}
__device__ __forceinline__ float4 fma4(float s, float4 a, float4 acc) {
    acc.x = fmaf(s, a.x, acc.x); acc.y = fmaf(s, a.y, acc.y);
    acc.z = fmaf(s, a.z, acc.z); acc.w = fmaf(s, a.w, acc.w);
    return acc;
}
// XCD swizzle: consecutive HW block ids round-robin across 8 XCDs; give each
// XCD a contiguous LOGICAL tile range so geometric neighbors share an L2.
__device__ __forceinline__ int swz(int b, int N) {
    return (b & 7) * (N >> 3) + (b >> 3);
}

// ---- setup kernels ----

__global__ __launch_bounds__(512) void k_tables(W21 wg, W21 wu, float* Sg, float* Su) {
    int x = threadIdx.x;
    float sg = 0.f, su = 0.f;
    #pragma unroll
    for (int d = -RAD; d <= RAD; ++d) {
        int xx = x + d;
        if (xx >= 0 && xx < W) { sg += wg.w[d + RAD]; su += wu.w[d + RAD]; }
    }
    Sg[x] = sg; Su[x] = su;
}

__global__ __launch_bounds__(256) void k_init(const float* __restrict__ img,
        const float4* __restrict__ unary, float* __restrict__ gray,
        float4* __restrict__ Q) {
    int b = swz(blockIdx.x, NPIX / 256);
    int p = b * 256 + threadIdx.x;
    float r = img[3 * p], g = img[3 * p + 1], bch = img[3 * p + 2];
    gray[p] = 0.2989f * r + 0.5870f * g + 0.1140f * bch;
    float4 u = unary[p];
    float mn = fminf(fminf(u.x, u.y), fminf(u.z, u.w));
    float ex = expf(mn - u.x), ey = expf(mn - u.y), ez = expf(mn - u.z), ew = expf(mn - u.w);
    float inv = 1.f / (ex + ey + ez + ew);
    Q[p] = f4(ex * inv, ey * inv, ez * inv, ew * inv);
}

// fused 2D conv of {gray, gray^2} -> mean_I, inv_var, a1b1
__global__ __launch_bounds__(256) void k_s1(const float* __restrict__ gray,
        const float* __restrict__ Su, float* __restrict__ mean_I,
        float* __restrict__ inv_var, float2* __restrict__ a1b1,
        W21 wu, float c0u) {
    __shared__ float  sg[RIN][CIN];
    __shared__ float2 ii[TY][CIN];
    int L = swz(blockIdx.x, NBLK);
    int x0 = (L & (GX - 1)) * TX, y0 = (L >> 4) * TY;
    int t = threadIdx.x;
    for (int i = t; i < RIN * CIN; i += 256) {
        int r = i / CIN, c = i - r * CIN;
        int gx = x0 + c - RAD, gy = y0 + r - RAD;
        float g = 0.f;
        if ((unsigned)gx < W && (unsigned)gy < H) g = gray[gy * W + gx];
        sg[r][c] = g;
    }
    __syncthreads();
    for (int i = t; i < TY * CIN; i += 256) {
        int r = i / CIN, c = i - r * CIN;
        float vI = 0.f, vII = 0.f;
        #pragma unroll
        for (int d = 0; d < KS; ++d) {
            float g = sg[r + d][c];
            vI = fmaf(wu.w[d], g, vI);
            vII = fmaf(wu.w[d] * g, g, vII);
        }
        ii[r][c] = make_float2(vI, vII);
    }
    __syncthreads();
    int k = t & 15, ty = t >> 4, cb = 2 * k;
    float2 a0 = make_float2(0.f, 0.f), a1 = a0;
    #pragma unroll
    for (int d = 0; d < KS + 1; ++d) {
        float2 v = ii[ty][cb + d];
        if (d < KS) { a0.x = fmaf(wu.w[d], v.x, a0.x); a0.y = fmaf(wu.w[d], v.y, a0.y); }
        if (d > 0)  { a1.x = fmaf(wu.w[d-1], v.x, a1.x); a1.y = fmaf(wu.w[d-1], v.y, a1.y); }
    }
    int py = y0 + ty;
    float Suy = Su[py];
    #pragma unroll
    for (int j = 0; j < 2; ++j) {
        float2 acc = j ? a1 : a0;
        int px = x0 + cb + j;
        int p = py * W + px;
        float gc = sg[ty + RAD][cb + j + RAD];
        float mI = acc.x - c0u * gc;
        float mII = acc.y - c0u * gc * gc;
        float iv = 1.f / ((mII - mI * mI) + CRF_EPS);
        float N = Su[px] * Suy - c0u;
        float av = mI * (1.f - N) * iv;
        float bv = N - av * mI;
        mean_I[p] = mI; inv_var[p] = iv; a1b1[p] = make_float2(av, bv);
    }
}

// fused 2D conv of a1b1 -> inv_bilateral_norm
__global__ __launch_bounds__(256) void k_s2(const float2* __restrict__ a1b1,
        const float* __restrict__ gray, float* __restrict__ inv_bn,
        W21 wu, float c0u) {
    __shared__ float2 s2[RIN][CIN];
    __shared__ float2 ii[TY][CIN];
    int L = swz(blockIdx.x, NBLK);
    int x0 = (L & (GX - 1)) * TX, y0 = (L >> 4) * TY;
    int t = threadIdx.x;
    for (int i = t; i < RIN * CIN; i += 256) {
        int r = i / CIN, c = i - r * CIN;
        int gx = x0 + c - RAD, gy = y0 + r - RAD;
        float2 v = make_float2(0.f, 0.f);
        if ((unsigned)gx < W && (unsigned)gy < H) v = a1b1[gy * W + gx];
        s2[r][c] = v;
    }
    __syncthreads();
    for (int i = t; i < TY * CIN; i += 256) {
        int r = i / CIN, c = i - r * CIN;
        float va = 0.f, vb = 0.f;
        #pragma unroll
        for (int d = 0; d < KS; ++d) {
            float2 v = s2[r + d][c];
            va = fmaf(wu.w[d], v.x, va);
            vb = fmaf(wu.w[d], v.y, vb);
        }
        ii[r][c] = make_float2(va, vb);
    }
    __syncthreads();
    int k = t & 15, ty = t >> 4, cb = 2 * k;
    float2 a0 = make_float2(0.f, 0.f), a1 = a0;
    #pragma unroll
    for (int d = 0; d < KS + 1; ++d) {
        float2 v = ii[ty][cb + d];
        if (d < KS) { a0.x = fmaf(wu.w[d], v.x, a0.x); a0.y = fmaf(wu.w[d], v.y, a0.y); }
        if (d > 0)  { a1.x = fmaf(wu.w[d-1], v.x, a1.x); a1.y = fmaf(wu.w[d-1], v.y, a1.y); }
    }
    int py = y0 + ty;
    #pragma unroll
    for (int j = 0; j < 2; ++j) {
        float2 acc = j ? a1 : a0;
        int px = x0 + cb + j;
        int p = py * W + px;
        float2 cen = s2[ty + RAD][cb + j + RAD];
        float va = acc.x - c0u * cen.x;
        float vb = acc.y - c0u * cen.y;
        inv_bn[p] = 1.f / (va * gray[p] + vb);
    }
}

// ---- iteration kernels ----

// F1: Q -> a, b, partial.  V-conv (3 arrays) into LDS, H-conv, pointwise.
__global__ __launch_bounds__(256) void k_f1(const float4* __restrict__ Q,
        const float* __restrict__ gray, const float* __restrict__ mean_I,
        const float* __restrict__ inv_var, const float* __restrict__ Sg,
        const float4* __restrict__ unary, float4* __restrict__ a_out,
        float4* __restrict__ b_out, float4* __restrict__ partial,
        W21 wg, W21 wu, float c0g, float c0u) {
    __shared__ float4 sQ[RIN][CIN];   // 29.9 KB
    __shared__ float  sG[RIN][CIN];   //  7.3 KB
    __shared__ float4 i0[TY][CIN];    // 13.3 KB  gauss(Q) V-pass
    __shared__ float4 i1[TY][CIN];    // 13.3 KB  guided(Q) V-pass
    __shared__ float4 i2[TY][CIN];    // 13.3 KB  guided(gray*Q) V-pass
    int L = swz(blockIdx.x, NBLK);
    int x0 = (L & (GX - 1)) * TX, y0 = (L >> 4) * TY;
    int t = threadIdx.x;
    for (int i = t; i < RIN * CIN; i += 256) {
        int r = i / CIN, c = i - r * CIN;
        int gx = x0 + c - RAD, gy = y0 + r - RAD;
        float4 q = f4(0.f, 0.f, 0.f, 0.f); float g = 0.f;
        if ((unsigned)gx < W && (unsigned)gy < H) {
            int p = gy * W + gx; q = Q[p]; g = gray[p];
        }
        sQ[r][c] = q; sG[r][c] = g;
    }
    __syncthreads();
    for (int i = t; i < TY * CIN; i += 256) {
        int r = i / CIN, c = i - r * CIN;
        float4 a0 = f4(0,0,0,0), a1 = a0, a2 = a0;
        #pragma unroll
        for (int d = 0; d < KS; ++d) {
            float4 q = sQ[r + d][c]; float g = sG[r + d][c];
            a0 = fma4(wg.w[d], q, a0);
            a1 = fma4(wu.w[d], q, a1);
            a2 = fma4(wu.w[d] * g, q, a2);
        }
        i0[r][c] = a0; i1[r][c] = a1; i2[r][c] = a2;
    }
    __syncthreads();
    int k = t & 15, ty = t >> 4, cb = 2 * k;
    float4 A0[2], A1[2], A2[2];
    #pragma unroll
    for (int j = 0; j < 2; ++j) { A0[j] = f4(0,0,0,0); A1[j] = A0[j]; A2[j] = A0[j]; }
    #pragma unroll
    for (int d = 0; d < KS + 1; ++d) {
        float4 v0 = i0[ty][cb + d], v1 = i1[ty][cb + d], v2 = i2[ty][cb + d];
        if (d < KS) {
            A0[0] = fma4(wg.w[d], v0, A0[0]);
            A1[0] = fma4(wu.w[d], v1, A1[0]);
            A2[0] = fma4(wu.w[d], v2, A2[0]);
        }
        if (d > 0) {
            A0[1] = fma4(wg.w[d-1], v0, A0[1]);
            A1[1] = fma4(wu.w[d-1], v1, A1[1]);
            A2[1] = fma4(wu.w[d-1], v2, A2[1]);
        }
    }
    int py = y0 + ty;
    float Sgy = Sg[py];
    #pragma unroll
    for (int j = 0; j < 2; ++j) {
        int px = x0 + cb + j;
        int p = py * W + px;
        float4 Qc = sQ[ty + RAD][cb + j + RAD];
        float gc = sG[ty + RAD][cb + j + RAD];
        float4 g4  = fma4(-c0g, Qc, A0[j]);
        float4 m4  = fma4(-c0u, Qc, A1[j]);
        float4 mi4 = fma4(-c0u * gc, Qc, A2[j]);
        float mI = mean_I[p], iv = inv_var[p];
        float4 a, b;
        a.x = (mi4.x - mI * m4.x) * iv; a.y = (mi4.y - mI * m4.y) * iv;
        a.z = (mi4.z - mI * m4.z) * iv; a.w = (mi4.w - mI * m4.w) * iv;
        b.x = m4.x - a.x * mI; b.y = m4.y - a.y * mI;
        b.z = m4.z - a.z * mI; b.w = m4.w - a.w * mI;
        float s3 = 3.f / (Sg[px] * Sgy - c0g);
        float4 u = unary[p];
        float4 part = f4(fmaf(s3, g4.x, -u.x), fmaf(s3, g4.y, -u.y),
                         fmaf(s3, g4.z, -u.z), fmaf(s3, g4.w, -u.w));
        a_out[p] = a; b_out[p] = b; partial[p] = part;
    }
}

// F2: a,b -> message + softmax -> Qout.  Sequential a/b tile phases.
__global__ __launch_bounds__(256) void k_f2(const float4* __restrict__ A,
        const float4* __restrict__ B, const float4* __restrict__ partial,
        const float* __restrict__ gray, const float* __restrict__ inv_bn,
        float4* __restrict__ Qout, W21 wu, float c0u) {
    __shared__ float4 sT[RIN][CIN];   // 29.9 KB (a then b)
    __shared__ float4 ia[TY][CIN];    // 13.3 KB
    __shared__ float4 ib[TY][CIN];    // 13.3 KB
    int L = swz(blockIdx.x, NBLK);
    int x0 = (L & (GX - 1)) * TX, y0 = (L >> 4) * TY;
    int t = threadIdx.x;
    int k = t & 15, ty = t >> 4, cb = 2 * k;
    // --- phase A ---
    for (int i = t; i < RIN * CIN; i += 256) {
        int r = i / CIN, c = i - r * CIN;
        int gx = x0 + c - RAD, gy = y0 + r - RAD;
        float4 v = f4(0.f, 0.f, 0.f, 0.f);
        if ((unsigned)gx < W && (unsigned)gy < H) v = A[gy * W + gx];
        sT[r][c] = v;
    }
    __syncthreads();
    float4 Ac[2];
    Ac[0] = sT[ty + RAD][cb + RAD]; Ac[1] = sT[ty + RAD][cb + 1 + RAD];
    for (int i = t; i < TY * CIN; i += 256) {
        int r = i / CIN, c = i - r * CIN;
        float4 acc = f4(0,0,0,0);
        #pragma unroll
        for (int d = 0; d < KS; ++d) acc = fma4(wu.w[d], sT[r + d][c], acc);
        ia[r][c] = acc;
    }
    __syncthreads();
    // --- phase B ---
    for (int i = t; i < RIN * CIN; i += 256) {
        int r = i / CIN, c = i - r * CIN;
        int gx = x0 + c - RAD, gy = y0 + r - RAD;
        float4 v = f4(0.f, 0.f, 0.f, 0.f);
        if ((unsigned)gx < W && (unsigned)gy < H) v = B[gy * W + gx];
        sT[r][c] = v;
    }
    __syncthreads();
    float4 Bc[2];
    Bc[0] = sT[ty + RAD][cb + RAD]; Bc[1] = sT[ty + RAD][cb + 1 + RAD];
    for (int i = t; i < TY * CIN; i += 256) {
        int r = i / CIN, c = i - r * CIN;
        float4 acc = f4(0,0,0,0);
        #pragma unroll
        for (int d = 0; d < KS; ++d) acc = fma4(wu.w[d], sT[r + d][c], acc);
        ib[r][c] = acc;
    }
    __syncthreads();
    // --- H-conv + message + softmax ---
    float4 VA[2], VB[2];
    #pragma unroll
    for (int j = 0; j < 2; ++j) { VA[j] = f4(0,0,0,0); VB[j] = VA[j]; }
    #pragma unroll
    for (int d = 0; d < KS + 1; ++d) {
        float4 va = ia[ty][cb + d], vb = ib[ty][cb + d];
        if (d < KS) { VA[0] = fma4(wu.w[d], va, VA[0]); VB[0] = fma4(wu.w[d], vb, VB[0]); }
        if (d > 0)  { VA[1] = fma4(wu.w[d-1], va, VA[1]); VB[1] = fma4(wu.w[d-1], vb, VB[1]); }
    }
    int py = y0 + ty;
    #pragma unroll
    for (int j = 0; j < 2; ++j) {
        int px = x0 + cb + j;
        int p = py * W + px;
        float4 a4 = fma4(-c0u, Ac[j], VA[j]);
        float4 b4 = fma4(-c0u, Bc[j], VB[j]);
        float gv = gray[p];
        float ibn = 10.f * inv_bn[p];
        float4 part = partial[p];
        float lx = fmaf(fmaf(a4.x, gv, b4.x), ibn, part.x);
        float ly = fmaf(fmaf(a4.y, gv, b4.y), ibn, part.y);
        float lz = fmaf(fmaf(a4.z, gv, b4.z), ibn, part.z);
        float lw = fmaf(fmaf(a4.w, gv, b4.w), ibn, part.w);
        float m = fmaxf(fmaxf(lx, ly), fmaxf(lz, lw));
        float ex = expf(lx - m), ey = expf(ly - m), ez = expf(lz - m), ew = expf(lw - m);
        float inv = 1.f / (ex + ey + ez + ew);
        Qout[p] = f4(ex * inv, ey * inv, ez * inv, ew * inv);
    }
}

// ---- host ----

static void make_w_host(double theta, W21* w, float* c0) {
    double tmp[KS], s = 0.0;
    for (int d = -RAD; d <= RAD; ++d) {
        double v = exp(-(double)(d * d) / (2.0 * theta * theta));
        tmp[d + RAD] = v; s += v;
    }
    for (int i = 0; i < KS; ++i) w->w[i] = (float)(tmp[i] / s);
    *c0 = (float)(1.0 / (s * s));   // normalized 2D center weight
}

extern "C" void kernel_launch(void* const* d_in, const int* in_sizes, int n_in,
                              void* d_out, int out_size, void* d_ws, size_t ws_size,
                              hipStream_t stream) {
    const float4* unary = (const float4*)d_in[0];
    const float* image = (const float*)d_in[1];
    float* wsf = (float*)d_ws;

    float*  gray    = wsf;
    float*  mean_I  = wsf + 262144;
    float*  inv_var = wsf + 524288;
    float2* a1b1    = (float2*)(wsf + 786432);
    float*  inv_bn  = wsf + 1310720;
    float*  Sg      = wsf + 1572864;
    float*  Su      = wsf + 1573376;
    float4* Q       = (float4*)(wsf + 1573888);
    float4* partial = (float4*)(wsf + 2622464);
    float4* a_arr   = (float4*)(wsf + 3671040);
    float4* b_arr   = (float4*)(wsf + 4719616);

    W21 wg, wu; float c0g, c0u;
    make_w_host(2.5, &wg, &c0g);
    make_w_host(10.0 / 3.0, &wu, &c0u);

    dim3 bl(256), grEl(NPIX / 256), grT(NBLK);

    k_tables<<<dim3(1), dim3(512), 0, stream>>>(wg, wu, Sg, Su);
    k_init<<<grEl, bl, 0, stream>>>(image, unary, gray, Q);
    k_s1<<<grT, bl, 0, stream>>>(gray, Su, mean_I, inv_var, a1b1, wu, c0u);
    k_s2<<<grT, bl, 0, stream>>>(a1b1, gray, inv_bn, wu, c0u);

    for (int it = 0; it < 5; ++it) {
        k_f1<<<grT, bl, 0, stream>>>((const float4*)Q, gray, mean_I, inv_var, Sg,
                                     unary, a_arr, b_arr, partial, wg, wu, c0g, c0u);
        float4* qdst = (it == 4) ? (float4*)d_out : Q;
        k_f2<<<grT, bl, 0, stream>>>(a_arr, b_arr, partial, gray, inv_bn, qdst,
                                     wu, c0u);
    }
}